// Round 6
// baseline (261.317 us; speedup 1.0000x reference)
//
#include <hip/hip_runtime.h>

// Multi-scale deformable attention forward — fused single kernel (R11).
// value:              (N, Lin, nH, D)        float32
// spatial_shapes:     (L, 2)                 int32/int64 (runtime-detected)
// level_start_index:  (L,)                   int32/int64 (runtime-detected)
// sampling_locations: (N, Lq, nH, L, P, 2)   float32
// attention_weights:  (N, Lq, nH, L, P)      float32
// out:                (N, Lq, nH*D)          float32
//
// R11 rationale: msda pinned at ~42us across 3 schedules (R1/R3/R5) with no
// pipe >50% -> vector-memory request-processing bound (~8.6M line requests).
// The fp16 prepass (conv, ~11-18us SERIAL) only reduced bytes, not requests
// -> fuse: gather fp32 value directly. Each corner cell = 128B = exactly one
// aligned cache line, read by 8 lanes x 16B. Unit = 8 lanes (1 query-head),
// lane j owns channels d in [4j, 4j+4). No fp16 repack, no shfl merge.
// L2/XCD footprint: 2 slabs x 1.44MB = 2.88MB <= 4MB -> gathers L2-resident.
#define NH 8
#define DD 32
#define LL 4
#define PP 4

typedef float  f32x4  __attribute__((ext_vector_type(4)));
typedef float  f32x2  __attribute__((ext_vector_type(2)));
typedef int    i32x4  __attribute__((ext_vector_type(4)));

#define SB() __builtin_amdgcn_sched_barrier(0)

// Block = one (n,h) slab x 32 queries; blockIdx&7 -> XCD (each XCD's L2 holds
// 2 slabs); slab-major chunk order (R5, neutral but harmless).
// Phase 1: coordinate math once per (unit,point) -> LDS entries
//   e_top = {off00, off01, w00, w01}, e_bot = {off10, off11, w10, w11}
//   (byte offsets of the 4 corner cells; bilinear*attention weights with
//   validity folded in). Stride 33 i32x4/unit -> conflict-free broadcast.
// Phase 2: per 2-point group: 4 ds_read_b128 (broadcast within unit) +
//   8 global_load_dwordx4 (one 128B line per corner, 8 lanes x 16B) +
//   32 v_fmac_f32. R8-style fence-pinned schedule, 16 loads in flight.
__global__ __attribute__((amdgpu_flat_work_group_size(256, 256)))
__attribute__((amdgpu_waves_per_eu(4)))
void msda_fwd_f(
    const float* __restrict__ value,
    const int*   __restrict__ ssh,
    const int*   __restrict__ lsi,
    const float* __restrict__ sloc,
    const float* __restrict__ aw,
    float*       __restrict__ out,
    int N, int Lq, int Lin, int spx, int chunks, int nSlabs)
{
    __shared__ i32x4 ent[32 * 33];   // 16896 B

    const int xcd   = blockIdx.x & 7;
    const int blk   = blockIdx.x >> 3;
    const int sw    = blk / chunks;            // slab-major per XCD
    const int chunk = blk % chunks;
    const int slab  = xcd * spx + sw;          // n*NH + h  (block-uniform)
    if (slab >= nSlabs) return;                // uniform -> barrier-safe

    const int t  = threadIdx.x;
    const int u  = t >> 3;                     // unit (query) within block
    const int j  = t & 7;
    const int q  = chunk * 32 + u;
    const int qc = min(q, Lq - 1);
    const int n  = slab >> 3;
    const int h  = slab & 7;

    // ---- phase 1: points p = 2j, 2j+1 of unit u ----
    {
        const size_t nqh = ((size_t)n * Lq + qc) * NH + h;
        const int l = j >> 1;                  // both points share a level
        const bool is64 = (ssh[1] == 0);
        const int W = is64 ? ssh[4 * l + 2] : ssh[2 * l + 1];
        const int H = is64 ? ssh[4 * l]     : ssh[2 * l];
        const int S = is64 ? lsi[2 * l]     : lsi[l];
        const f32x4 lc = __builtin_nontemporal_load((const f32x4*)sloc + nqh * 8 + j);
        const f32x2 av = __builtin_nontemporal_load((const f32x2*)aw + nqh * 8 + j);
        const float fW = (float)W, fH = (float)H;
        const int rowb = W * (NH * DD * 4);    // 1024 B per cell column step = W cells
        const int sbase = S * (NH * DD * 4);
#pragma unroll
        for (int pt = 0; pt < 2; ++pt) {
            const float x  = lc[2 * pt]     * fW - 0.5f;
            const float y  = lc[2 * pt + 1] * fH - 0.5f;
            const float wq = av[pt];
            const float x0f = floorf(x), y0f = floorf(y);
            const int x0 = (int)x0f, y0 = (int)y0f;
            const float dx = x - x0f, dy = y - y0f;
            const int x1 = x0 + 1, y1 = y0 + 1;
            const bool vx0 = (x0 >= 0) & (x0 < W), vx1 = (x1 >= 0) & (x1 < W);
            const bool vy0 = (y0 >= 0) & (y0 < H), vy1 = (y1 >= 0) & (y1 < H);
            const int cx0 = min(max(x0, 0), W - 1), cx1 = min(max(x1, 0), W - 1);
            const int cy0 = min(max(y0, 0), H - 1), cy1 = min(max(y1, 0), H - 1);
            const float wx0 = (1.f - dx) * wq * (vx0 ? 1.f : 0.f);
            const float wx1 = dx         * wq * (vx1 ? 1.f : 0.f);
            const float ty  = (1.f - dy) * (vy0 ? 1.f : 0.f);
            const float by  = dy         * (vy1 ? 1.f : 0.f);
            const int rt = cy0 * rowb + sbase;
            const int rb = cy1 * rowb + sbase;
            const int o0 = cx0 * (NH * DD * 4), o1 = cx1 * (NH * DD * 4);
            i32x4 et, eb;
            et.x = rt + o0;  et.y = rt + o1;
            et.z = __float_as_int(wx0 * ty);  et.w = __float_as_int(wx1 * ty);
            eb.x = rb + o0;  eb.y = rb + o1;
            eb.z = __float_as_int(wx0 * by);  eb.w = __float_as_int(wx1 * by);
            const int p = 2 * j + pt;
            ent[u * 33 + 2 * p]     = et;
            ent[u * 33 + 2 * p + 1] = eb;
        }
    }
    __syncthreads();
    if (q >= Lq) return;

    // ---- phase 2 ----
    // lane base: slab-n offset + head offset + channel offset (16B per lane)
    const char* __restrict__ sb =
        (const char*)value + (size_t)n * Lin * (NH * DD * 4) + h * (DD * 4) + j * 16;
    const int ub = u * 33;

    f32x4 acc = {0.f, 0.f, 0.f, 0.f};

    // group g covers points 2g, 2g+1 -> entries ub + 4g + {0,1,2,3}
#define RD2(g, E) { \
    E[0] = ent[ub + 4 * (g) + 0]; \
    E[1] = ent[ub + 4 * (g) + 1]; \
    E[2] = ent[ub + 4 * (g) + 2]; \
    E[3] = ent[ub + 4 * (g) + 3]; }
#define LD2(E, V) _Pragma("unroll") \
    for (int i = 0; i < 4; ++i) { \
        V[2*i]   = *(const f32x4*)(sb + (unsigned)E[i].x); \
        V[2*i+1] = *(const f32x4*)(sb + (unsigned)E[i].y); }
#define AC2(E, V) _Pragma("unroll") \
    for (int i = 0; i < 4; ++i) { \
        const float wl = __int_as_float(E[i].z); \
        const float wr = __int_as_float(E[i].w); \
        _Pragma("unroll") for (int d = 0; d < 4; ++d) { \
            acc[d] += wl * V[2*i][d]; \
            acc[d] += wr * V[2*i+1][d]; } }

    // Fence-pinned schedule: 2 groups (16 loads) in flight, refill after
    // each consume. E/V double-buffered -> ~110 VGPR, fits 128 cap @4w/EU.
    i32x4 EA[4], EB[4];
    f32x4 V0[8], V1[8];
    RD2(0, EA) RD2(1, EB)
    SB();
    LD2(EA, V0) LD2(EB, V1)      // 16 outstanding
    SB();
    AC2(EA, V0) SB(); RD2(2, EA) SB(); LD2(EA, V0) SB();
    AC2(EB, V1) SB(); RD2(3, EB) SB(); LD2(EB, V1) SB();
    AC2(EA, V0) SB(); RD2(4, EA) SB(); LD2(EA, V0) SB();
    AC2(EB, V1) SB(); RD2(5, EB) SB(); LD2(EB, V1) SB();
    AC2(EA, V0) SB(); RD2(6, EA) SB(); LD2(EA, V0) SB();
    AC2(EB, V1) SB(); RD2(7, EB) SB(); LD2(EB, V1) SB();
    AC2(EA, V0)
    AC2(EB, V1)

    // lane j owns channels [4j, 4j+4): 8 lanes -> 128B contiguous store
    const size_t onqh = ((size_t)n * Lq + q) * NH + h;
    __builtin_nontemporal_store(acc, (f32x4*)(out + onqh * DD + j * 4));
}

extern "C" void kernel_launch(void* const* d_in, const int* in_sizes, int n_in,
                              void* d_out, int out_size, void* d_ws, size_t ws_size,
                              hipStream_t stream)
{
    const float* value = (const float*)d_in[0];
    const int*   ss    = (const int*)  d_in[1];
    const int*   lsi   = (const int*)  d_in[2];
    const float* sloc  = (const float*)d_in[3];
    const float* aw    = (const float*)d_in[4];
    float* out = (float*)d_out;

    const int N = 2;
    const int Lq  = in_sizes[4] / (N * NH * LL * PP);
    const int Lin = in_sizes[0] / (N * NH * DD);

    const int nSlabs = N * NH;              // 16
    const int spx    = (nSlabs + 7) / 8;    // slabs per XCD = 2
    const int chunks = (Lq + 31) / 32;
    const int grid   = 8 * spx * chunks;
    msda_fwd_f<<<grid, 256, 0, stream>>>(value, ss, lsi, sloc, aw, out,
                                         N, Lq, Lin, spx, chunks, nSlabs);
}

// Round 7
// 140.433 us; speedup vs baseline: 1.8608x; 1.8608x over previous
//
#include <hip/hip_runtime.h>

// Multi-scale deformable attention forward.
// value:              (N, Lin, nH, D)        float32
// spatial_shapes:     (L, 2)                 int32/int64 (runtime-detected)
// level_start_index:  (L,)                   int32/int64 (runtime-detected)
// sampling_locations: (N, Lq, nH, L, P, 2)   float32
// attention_weights:  (N, Lq, nH, L, P)      float32
// out:                (N, Lq, nH*D)          float32
#define NH 8
#define DD 32
#define LL 4
#define PP 4

typedef float  f32x4  __attribute__((ext_vector_type(4)));
typedef float  f32x2  __attribute__((ext_vector_type(2)));
typedef int    i32x4  __attribute__((ext_vector_type(4)));
typedef _Float16 half4v __attribute__((ext_vector_type(4)));

// ---------------- prepass: value (n,pos,h,d) fp32 -> (n,h,pos,d) fp16 ----------------
// R12 note: R6 proved this prepass's value is the SLAB-CONTIGUOUS layout
// (fp32-direct gathers thrashed L2 sets at 1KB stride: FETCH 23->189MB),
// not the fp16 dtype per se. Keep it.
__global__ __launch_bounds__(256) void conv_kernel(
    const float* __restrict__ value, _Float16* __restrict__ vh,
    int Lin, int spx, int nSlabs)
{
    const int xcd  = blockIdx.x & 7;
    const int blk  = blockIdx.x >> 3;
    const int sw   = blk % spx;
    const int seg  = blk / spx;
    const int slab = xcd * spx + sw;
    if (slab >= nSlabs) return;
    const int i = seg * 256 + threadIdx.x;          // over Lin*8 chunks
    if (i >= Lin * 8) return;
    const int d4  = i & 7;
    const int pos = i >> 3;
    const int n   = slab >> 3;
    const int h   = slab & 7;

    const f32x4 v = __builtin_nontemporal_load(
        (const f32x4*)(value + (((size_t)n * Lin + pos) * NH + h) * DD + d4 * 4));
    half4v o;
    o.x = (_Float16)v.x; o.y = (_Float16)v.y; o.z = (_Float16)v.z; o.w = (_Float16)v.w;
    // NOT nontemporal: vh must stay resident in this XCD's L2 for the gathers.
    *(half4v*)(vh + ((size_t)slab * Lin + pos) * DD + d4 * 4) = o;
}

// acc(f32) += f16(lo/hi half of DW) * W(f32)  — single v_fma_mix_f32.
#define FMAMIX_LO(ACC, DW, W) \
    asm("v_fma_mix_f32 %0, %1, %2, %0 op_sel:[0,0,0] op_sel_hi:[1,0,0]" \
        : "+v"(ACC) : "v"(DW), "v"(W))
#define FMAMIX_HI(ACC, DW, W) \
    asm("v_fma_mix_f32 %0, %1, %2, %0 op_sel:[1,0,0] op_sel_hi:[1,0,0]" \
        : "+v"(ACC) : "v"(DW), "v"(W))

#define SB() __builtin_amdgcn_sched_barrier(0)

// ---------------- main kernel ----------------
// R12 (on R5 base = best verified, msda ~42us):
// (1) NO __syncthreads: a unit = 8 contiguous lanes, so LDS entry
//     write->read is intra-wave; LDS ops complete in order within a wave
//     (lgkmcnt), so producer/consumer and chunk-to-chunk WAR are safe.
// (2) 2 chunks per block, BOTH chunks' sloc/aw loaded upfront: chunk 1's
//     phase-1 HBM latency hides under chunk 0's gathers. ent rows reused.
// Everything else identical to R5: XCD pinning, slab-major order,
// fp16 slab-contiguous vh, fence-pinned 16-deep gather pipeline.
__global__ __attribute__((amdgpu_flat_work_group_size(256, 256)))
__attribute__((amdgpu_waves_per_eu(4)))
void msda_fwd_h(
    const _Float16* __restrict__ vh,
    const int*   __restrict__ ssh,
    const int*   __restrict__ lsi,
    const float* __restrict__ sloc,
    const float* __restrict__ aw,
    float*       __restrict__ out,
    int N, int Lq, int Lin, int spx, int half, int nSlabs)
{
    __shared__ i32x4 ent[32 * 39];   // 19968 B

    const int xcd  = blockIdx.x & 7;
    const int blk  = blockIdx.x >> 3;
    const int sw   = blk / half;               // slab-major per XCD
    const int c2   = blk % half;
    const int slab = xcd * spx + sw;           // n*NH + h  (block-uniform)
    if (slab >= nSlabs) return;

    const int t  = threadIdx.x;
    const int u  = t >> 3;                     // unit (query) within block
    const int j  = t & 7;
    const int n  = slab >> 3;
    const int h  = slab & 7;

    const int q0 = (2 * c2) * 32 + u;
    const int q1 = (2 * c2 + 1) * 32 + u;
    const int q0c = min(q0, Lq - 1);
    const int q1c = min(q1, Lq - 1);

    // ---- upfront loads for BOTH chunks (latency of chunk1 hides under chunk0) ----
    const size_t nqh0 = ((size_t)n * Lq + q0c) * NH + h;
    const size_t nqh1 = ((size_t)n * Lq + q1c) * NH + h;
    const f32x4 lc0 = __builtin_nontemporal_load((const f32x4*)sloc + nqh0 * 8 + j);
    const f32x2 av0 = __builtin_nontemporal_load((const f32x2*)aw + nqh0 * 8 + j);
    const f32x4 lc1 = __builtin_nontemporal_load((const f32x4*)sloc + nqh1 * 8 + j);
    const f32x2 av1 = __builtin_nontemporal_load((const f32x2*)aw + nqh1 * 8 + j);

    // level constants (per j)
    const int l = j >> 1;
    const bool is64 = (ssh[1] == 0);
    const int W = is64 ? ssh[4 * l + 2] : ssh[2 * l + 1];
    const int H = is64 ? ssh[4 * l]     : ssh[2 * l];
    const int S = is64 ? lsi[2 * l]     : lsi[l];
    const float fW = (float)W, fH = (float)H;
    const int rowb  = W * (DD * 2);
    const int sbase = S * (DD * 2);

    // phase-1 body: entries for points 2j, 2j+1 of unit u from (LC, AV)
#define PHASE1(LC, AV) { \
        _Pragma("unroll") \
        for (int pt = 0; pt < 2; ++pt) { \
            const float x  = LC[2 * pt]     * fW - 0.5f; \
            const float y  = LC[2 * pt + 1] * fH - 0.5f; \
            const float wq = AV[pt]; \
            const float x0f = floorf(x), y0f = floorf(y); \
            const int x0 = (int)x0f, y0 = (int)y0f; \
            const float dx = x - x0f, dy = y - y0f; \
            const int x1 = x0 + 1, y1 = y0 + 1; \
            const bool vx0 = (x0 >= 0) & (x0 < W), vx1 = (x1 >= 0) & (x1 < W); \
            const bool vy0 = (y0 >= 0) & (y0 < H), vy1 = (y1 >= 0) & (y1 < H); \
            const int cx0 = min(max(x0, 0), W - 1), cx1 = min(max(x1, 0), W - 1); \
            const int cy0 = min(max(y0, 0), H - 1), cy1 = min(max(y1, 0), H - 1); \
            const float wx0 = (1.f - dx) * wq * (vx0 ? 1.f : 0.f); \
            const float wx1 = dx         * wq * (vx1 ? 1.f : 0.f); \
            const float ty  = (1.f - dy) * (vy0 ? 1.f : 0.f); \
            const float by  = dy         * (vy1 ? 1.f : 0.f); \
            const int rt = cy0 * rowb + sbase; \
            const int rb = cy1 * rowb + sbase; \
            i32x4 e0, e1; \
            e0.x = rt + cx0 * (DD * 2);  e0.y = rb + cx0 * (DD * 2); \
            e0.z = __float_as_int(wx0 * ty);  e0.w = __float_as_int(wx0 * by); \
            e1.x = rt + cx1 * (DD * 2);  e1.y = rb + cx1 * (DD * 2); \
            e1.z = __float_as_int(wx1 * ty);  e1.w = __float_as_int(wx1 * by); \
            const int base = u * 39 + 5 * j + 2 * pt; \
            ent[base]     = e0; \
            ent[base + 1] = e1; \
        } }

    // ---- phase 2 machinery ----
    const int side = j >> 2;
    const int cg   = j & 3;
    const char* __restrict__ sb =
        (const char*)vh + (size_t)slab * Lin * (DD * 2) + cg * 16;  // saddr + lane base
    const int ub = u * 39 + side;

    // entry for point p=4b+i: idx = ub + 10b + {0,2,5,7}[i]
#define RD(b, E) { \
    E[0] = ent[ub + 10 * (b) + 0]; \
    E[1] = ent[ub + 10 * (b) + 2]; \
    E[2] = ent[ub + 10 * (b) + 5]; \
    E[3] = ent[ub + 10 * (b) + 7]; }
#define LD(E, V) _Pragma("unroll") \
    for (int i = 0; i < 4; ++i) { \
        V[2*i]   = *(const i32x4*)(sb + (unsigned)E[i].x); \
        V[2*i+1] = *(const i32x4*)(sb + (unsigned)E[i].y); }
#define AC(E, V) _Pragma("unroll") \
    for (int i = 0; i < 4; ++i) { \
        const float wt = __int_as_float(E[i].z); \
        const float wb = __int_as_float(E[i].w); \
        _Pragma("unroll") for (int d = 0; d < 4; ++d) { \
            FMAMIX_LO(acc[2*d],   V[2*i][d],   wt); \
            FMAMIX_HI(acc[2*d+1], V[2*i][d],   wt); \
            FMAMIX_LO(acc[2*d],   V[2*i+1][d], wb); \
            FMAMIX_HI(acc[2*d+1], V[2*i+1][d], wb); } }

    // R8 fence-pinned pipeline: 16 loads in flight, 8-deep sustained.
#define PHASE2() { \
    i32x4 E0[4], E1[4], E2[4], E3[4]; \
    i32x4 V0[8], V1[8]; \
    RD(0, E0) RD(1, E1) \
    SB(); \
    LD(E0, V0) LD(E1, V1) \
    SB(); \
    AC(E0, V0) \
    RD(2, E2) \
    SB(); \
    LD(E2, V0) \
    SB(); \
    AC(E1, V1) \
    RD(3, E3) \
    SB(); \
    LD(E3, V1) \
    SB(); \
    AC(E2, V0) \
    AC(E3, V1) }

#define MERGE_STORE(Q) { \
    _Pragma("unroll") \
    for (int k = 0; k < 8; ++k) \
        acc[k] += __shfl_xor(acc[k], 4); \
    if ((Q) < Lq) { \
        f32x4 st; \
        st.x = acc[side * 4 + 0]; \
        st.y = acc[side * 4 + 1]; \
        st.z = acc[side * 4 + 2]; \
        st.w = acc[side * 4 + 3]; \
        const size_t onqh = ((size_t)n * Lq + (Q)) * NH + h; \
        __builtin_nontemporal_store(st, (f32x4*)(out + onqh * DD + cg * 8 + side * 4)); \
    } }

    float acc[8];

    // ---- chunk 0 ----
    PHASE1(lc0, av0)
    // no barrier: producer lanes and consumer lanes share a wave; LDS is
    // in-order within a wave (compiler inserts lgkmcnt waits).
#pragma unroll
    for (int k = 0; k < 8; ++k) acc[k] = 0.f;
    PHASE2()
    MERGE_STORE(q0)

    // ---- chunk 1 (lc1/av1 already in registers; ent rows reused — WAR
    // is safe by in-order intra-wave LDS) ----
    PHASE1(lc1, av1)
#pragma unroll
    for (int k = 0; k < 8; ++k) acc[k] = 0.f;
    PHASE2()
    MERGE_STORE(q1)
}

// ---------------- fp32 fallback if ws too small ----------------
__global__ __launch_bounds__(256) void msda_fwd_f32(
    const float* __restrict__ value,
    const int*   __restrict__ spatial_shapes,
    const int*   __restrict__ level_start,
    const float* __restrict__ sloc,
    const float* __restrict__ aw,
    float*       __restrict__ out,
    int N, int Lq, int Lin, int total)
{
    int tid = blockIdx.x * blockDim.x + threadIdx.x;
    if (tid >= total) return;
    const int c  = tid & 7;
    const int h  = (tid >> 3) & 7;
    const int nq = tid >> 6;
    const int n  = nq / Lq;
    const bool is64 = (spatial_shapes[1] == 0);
    int Hs[LL], Ws[LL], Ss[LL];
#pragma unroll
    for (int l = 0; l < LL; ++l) {
        if (is64) { Hs[l] = spatial_shapes[4*l]; Ws[l] = spatial_shapes[4*l+2]; Ss[l] = level_start[2*l]; }
        else      { Hs[l] = spatial_shapes[2*l]; Ws[l] = spatial_shapes[2*l+1]; Ss[l] = level_start[l]; }
    }
    const size_t nqh = (size_t)nq * NH + h;
    const float* loc_p = sloc + nqh * (LL * PP * 2);
    const float* aw_p  = aw   + nqh * (LL * PP);
    float4 acc = make_float4(0.f, 0.f, 0.f, 0.f);
#pragma unroll
    for (int l = 0; l < LL; ++l) {
        const int H = Hs[l], W = Ws[l];
        const float* vb = value + (((size_t)n * Lin + Ss[l]) * NH + h) * DD + c * 4;
#pragma unroll
        for (int p = 0; p < PP; ++p) {
            const int jj = l * PP + p;
            const float x = loc_p[2*jj] * (float)W - 0.5f;
            const float y = loc_p[2*jj+1] * (float)H - 0.5f;
            const float w = aw_p[jj];
            const float x0f = floorf(x), y0f = floorf(y);
            const int x0 = (int)x0f, y0 = (int)y0f, x1 = x0+1, y1 = y0+1;
            const float dx = x - x0f, dy = y - y0f;
            const bool vx0 = x0>=0 && x0<W, vx1 = x1>=0 && x1<W;
            const bool vy0 = y0>=0 && y0<H, vy1 = y1>=0 && y1<H;
            const int cx0 = min(max(x0,0),W-1), cx1 = min(max(x1,0),W-1);
            const int cy0 = min(max(y0,0),H-1), cy1 = min(max(y1,0),H-1);
            const float w00 = (1.f-dx)*(1.f-dy)*w*((vx0&&vy0)?1.f:0.f);
            const float w01 = dx*(1.f-dy)*w*((vx1&&vy0)?1.f:0.f);
            const float w10 = (1.f-dx)*dy*w*((vx0&&vy1)?1.f:0.f);
            const float w11 = dx*dy*w*((vx1&&vy1)?1.f:0.f);
            const float4 v00 = *(const float4*)(vb + (size_t)(cy0*W+cx0)*(NH*DD));
            const float4 v01 = *(const float4*)(vb + (size_t)(cy0*W+cx1)*(NH*DD));
            const float4 v10 = *(const float4*)(vb + (size_t)(cy1*W+cx0)*(NH*DD));
            const float4 v11 = *(const float4*)(vb + (size_t)(cy1*W+cx1)*(NH*DD));
            acc.x += w00*v00.x + w01*v01.x + w10*v10.x + w11*v11.x;
            acc.y += w00*v00.y + w01*v01.y + w10*v10.y + w11*v11.y;
            acc.z += w00*v00.z + w01*v01.z + w10*v10.z + w11*v11.z;
            acc.w += w00*v00.w + w01*v01.w + w10*v10.w + w11*v11.w;
        }
    }
    *(float4*)(out + nqh * DD + c * 4) = acc;
}

extern "C" void kernel_launch(void* const* d_in, const int* in_sizes, int n_in,
                              void* d_out, int out_size, void* d_ws, size_t ws_size,
                              hipStream_t stream)
{
    const float* value = (const float*)d_in[0];
    const int*   ss    = (const int*)  d_in[1];
    const int*   lsi   = (const int*)  d_in[2];
    const float* sloc  = (const float*)d_in[3];
    const float* aw    = (const float*)d_in[4];
    float* out = (float*)d_out;

    const int N = 2;
    const int Lq  = in_sizes[4] / (N * NH * LL * PP);
    const int Lin = in_sizes[0] / (N * NH * DD);

    const size_t need = (size_t)N * NH * Lin * DD * sizeof(_Float16);
    if (ws_size >= need) {
        _Float16* vh = (_Float16*)d_ws;
        const int nSlabs = N * NH;              // 16
        const int spx    = (nSlabs + 7) / 8;    // slabs per XCD = 2
        const int segs   = (Lin * 8 + 255) / 256;
        conv_kernel<<<8 * spx * segs, 256, 0, stream>>>(value, vh, Lin, spx, nSlabs);

        const int chunks = (Lq + 31) / 32;
        const int half   = (chunks + 1) / 2;    // 2 chunks per block
        const int grid   = 8 * spx * half;
        msda_fwd_h<<<grid, 256, 0, stream>>>(vh, ss, lsi, sloc, aw, out,
                                             N, Lq, Lin, spx, half, nSlabs);
    } else {
        const int total = N * Lq * NH * 8;
        msda_fwd_f32<<<(total + 255) / 256, 256, 0, stream>>>(value, ss, lsi, sloc, aw, out,
                                                              N, Lq, Lin, total);
    }
}

// Round 8
// 132.332 us; speedup vs baseline: 1.9747x; 1.0612x over previous
//
#include <hip/hip_runtime.h>

// Multi-scale deformable attention forward.
// value:              (N, Lin, nH, D)        float32
// spatial_shapes:     (L, 2)                 int32/int64 (runtime-detected)
// level_start_index:  (L,)                   int32/int64 (runtime-detected)
// sampling_locations: (N, Lq, nH, L, P, 2)   float32
// attention_weights:  (N, Lq, nH, L, P)      float32
// out:                (N, Lq, nH*D)          float32
//
// R13 = exact revert to R5 (best verified: 131.5us total, msda ~41.5us).
// Evidence ledger:
//  - msda pinned at ~42us across 3 schedules (R1 shallow / R3 deep / R5) ->
//    scattered-gather request-throughput wall (11.5M x 64B requests,
//    ~45K/CU at ~2-3 cy each = 38-45us), NOT latency/occupancy-bound.
//  - R2 (waves_per_eu 8): VGPR 32, MLP collapsed, -14%.
//  - R4 (LDS-stage lv2+3): occupancy 18%, 1.6M bank conflicts, +40%.
//  - R6 (fused fp32 gather): L2 set-thrash at 1KB stride, FETCH 23->189MB, 4x.
//  - R7 (no-barrier 2-chunk): grid halved, +11%.
//  - ~82us of total is harness fillBuffer (present even with ws unused).
#define NH 8
#define DD 32
#define LL 4
#define PP 4

typedef float  f32x4  __attribute__((ext_vector_type(4)));
typedef float  f32x2  __attribute__((ext_vector_type(2)));
typedef int    i32x4  __attribute__((ext_vector_type(4)));
typedef _Float16 half4v __attribute__((ext_vector_type(4)));

// ---------------- prepass: value (n,pos,h,d) fp32 -> (n,h,pos,d) fp16 ----------------
// XCD-pinned like the main kernel so each vh slab is written by the XCD
// that will gather from it -> L2-warm at msda start. R6 proved the value of
// this prepass is the SLAB-CONTIGUOUS layout (fp32-direct thrashed L2 sets).
__global__ __launch_bounds__(256) void conv_kernel(
    const float* __restrict__ value, _Float16* __restrict__ vh,
    int Lin, int spx, int nSlabs)
{
    const int xcd  = blockIdx.x & 7;
    const int blk  = blockIdx.x >> 3;
    const int sw   = blk % spx;
    const int seg  = blk / spx;
    const int slab = xcd * spx + sw;
    if (slab >= nSlabs) return;
    const int i = seg * 256 + threadIdx.x;          // over Lin*8 chunks
    if (i >= Lin * 8) return;
    const int d4  = i & 7;
    const int pos = i >> 3;
    const int n   = slab >> 3;
    const int h   = slab & 7;

    const f32x4 v = __builtin_nontemporal_load(
        (const f32x4*)(value + (((size_t)n * Lin + pos) * NH + h) * DD + d4 * 4));
    half4v o;
    o.x = (_Float16)v.x; o.y = (_Float16)v.y; o.z = (_Float16)v.z; o.w = (_Float16)v.w;
    // NOT nontemporal: vh must stay resident in this XCD's L2 for the gathers.
    *(half4v*)(vh + ((size_t)slab * Lin + pos) * DD + d4 * 4) = o;
}

// acc(f32) += f16(lo/hi half of DW) * W(f32)  — single v_fma_mix_f32.
#define FMAMIX_LO(ACC, DW, W) \
    asm("v_fma_mix_f32 %0, %1, %2, %0 op_sel:[0,0,0] op_sel_hi:[1,0,0]" \
        : "+v"(ACC) : "v"(DW), "v"(W))
#define FMAMIX_HI(ACC, DW, W) \
    asm("v_fma_mix_f32 %0, %1, %2, %0 op_sel:[1,0,0] op_sel_hi:[1,0,0]" \
        : "+v"(ACC) : "v"(DW), "v"(W))

#define SB() __builtin_amdgcn_sched_barrier(0)

// ---------------- main kernel ----------------
// Block = one (n,h) slab x 32 queries; blockIdx&7 -> XCD so each XCD's L2
// holds only 2 slabs (1.44 MB) -> gathers stay L2-hit (FETCH at stream floor).
// Slab-major chunk order (R5). Phase 1: coordinate math once per
// (unit,point) -> LDS entries {off_top,off_bot,w_top,w_bot}, conflict-free.
// Phase 2: lane j (side=j>>2, cg=j&3): R8 fence-pinned 16-deep pipeline.
__global__ __attribute__((amdgpu_flat_work_group_size(256, 256)))
__attribute__((amdgpu_waves_per_eu(4)))
void msda_fwd_h(
    const _Float16* __restrict__ vh,
    const int*   __restrict__ ssh,
    const int*   __restrict__ lsi,
    const float* __restrict__ sloc,
    const float* __restrict__ aw,
    float*       __restrict__ out,
    int N, int Lq, int Lin, int spx, int chunks, int nSlabs)
{
    __shared__ i32x4 ent[32 * 39];   // 19968 B

    const int xcd   = blockIdx.x & 7;
    const int blk   = blockIdx.x >> 3;
    const int sw    = blk / chunks;            // slab-major: one slab at a time per XCD
    const int chunk = blk % chunks;
    const int slab  = xcd * spx + sw;          // n*NH + h  (block-uniform)
    if (slab >= nSlabs) return;                // uniform -> barrier-safe

    const int t  = threadIdx.x;
    const int u  = t >> 3;                     // unit (query) within block
    const int j  = t & 7;
    const int q  = chunk * 32 + u;
    const int qc = min(q, Lq - 1);
    const int n  = slab >> 3;
    const int h  = slab & 7;

    // ---- phase 1: points p = 2j, 2j+1 of unit u (both sides) ----
    {
        const size_t nqh = ((size_t)n * Lq + qc) * NH + h;
        const int l = j >> 1;                  // both points share a level
        const bool is64 = (ssh[1] == 0);
        const int W = is64 ? ssh[4 * l + 2] : ssh[2 * l + 1];
        const int H = is64 ? ssh[4 * l]     : ssh[2 * l];
        const int S = is64 ? lsi[2 * l]     : lsi[l];
        const f32x4 lc = __builtin_nontemporal_load((const f32x4*)sloc + nqh * 8 + j);
        const f32x2 av = __builtin_nontemporal_load((const f32x2*)aw + nqh * 8 + j);
        const float fW = (float)W, fH = (float)H;
        const int rowb  = W * (DD * 2);
        const int sbase = S * (DD * 2);
#pragma unroll
        for (int pt = 0; pt < 2; ++pt) {
            const float x  = lc[2 * pt]     * fW - 0.5f;
            const float y  = lc[2 * pt + 1] * fH - 0.5f;
            const float wq = av[pt];
            const float x0f = floorf(x), y0f = floorf(y);
            const int x0 = (int)x0f, y0 = (int)y0f;
            const float dx = x - x0f, dy = y - y0f;
            const int x1 = x0 + 1, y1 = y0 + 1;
            const bool vx0 = (x0 >= 0) & (x0 < W), vx1 = (x1 >= 0) & (x1 < W);
            const bool vy0 = (y0 >= 0) & (y0 < H), vy1 = (y1 >= 0) & (y1 < H);
            const int cx0 = min(max(x0, 0), W - 1), cx1 = min(max(x1, 0), W - 1);
            const int cy0 = min(max(y0, 0), H - 1), cy1 = min(max(y1, 0), H - 1);
            const float wx0 = (1.f - dx) * wq * (vx0 ? 1.f : 0.f);
            const float wx1 = dx         * wq * (vx1 ? 1.f : 0.f);
            const float ty  = (1.f - dy) * (vy0 ? 1.f : 0.f);
            const float by  = dy         * (vy1 ? 1.f : 0.f);
            const int rt = cy0 * rowb + sbase;
            const int rb = cy1 * rowb + sbase;
            i32x4 e0, e1;
            e0.x = rt + cx0 * (DD * 2);  e0.y = rb + cx0 * (DD * 2);
            e0.z = __float_as_int(wx0 * ty);  e0.w = __float_as_int(wx0 * by);
            e1.x = rt + cx1 * (DD * 2);  e1.y = rb + cx1 * (DD * 2);
            e1.z = __float_as_int(wx1 * ty);  e1.w = __float_as_int(wx1 * by);
            const int base = u * 39 + 5 * j + 2 * pt;
            ent[base]     = e0;
            ent[base + 1] = e1;
        }
    }
    __syncthreads();
    if (q >= Lq) return;

    // ---- phase 2 ----
    const int side = j >> 2;
    const int cg   = j & 3;
    const char* __restrict__ sb =
        (const char*)vh + (size_t)slab * Lin * (DD * 2) + cg * 16;  // saddr + lane base
    const int ub = u * 39 + side;

    float acc[8];
#pragma unroll
    for (int k = 0; k < 8; ++k) acc[k] = 0.f;

    // entry for point p=4b+i: idx = ub + 10b + {0,2,5,7}[i]
#define RD(b, E) { \
    E[0] = ent[ub + 10 * (b) + 0]; \
    E[1] = ent[ub + 10 * (b) + 2]; \
    E[2] = ent[ub + 10 * (b) + 5]; \
    E[3] = ent[ub + 10 * (b) + 7]; }
#define LD(E, V) _Pragma("unroll") \
    for (int i = 0; i < 4; ++i) { \
        V[2*i]   = *(const i32x4*)(sb + (unsigned)E[i].x); \
        V[2*i+1] = *(const i32x4*)(sb + (unsigned)E[i].y); }
#define AC(E, V) _Pragma("unroll") \
    for (int i = 0; i < 4; ++i) { \
        const float wt = __int_as_float(E[i].z); \
        const float wb = __int_as_float(E[i].w); \
        _Pragma("unroll") for (int d = 0; d < 4; ++d) { \
            FMAMIX_LO(acc[2*d],   V[2*i][d],   wt); \
            FMAMIX_HI(acc[2*d+1], V[2*i][d],   wt); \
            FMAMIX_LO(acc[2*d],   V[2*i+1][d], wb); \
            FMAMIX_HI(acc[2*d+1], V[2*i+1][d], wb); } }

    // R8 schedule: 16 loads in flight, then 8-deep sustained.
    // sched_barrier(0) fences stop the scheduler from collapsing the
    // pipeline to save registers (R1/R2 failure mode).
    i32x4 E0[4], E1[4], E2[4], E3[4];
    i32x4 V0[8], V1[8];
    RD(0, E0) RD(1, E1)        // 8 ds_read_b128
    SB();
    LD(E0, V0) LD(E1, V1)      // 16 global_load_dwordx4 outstanding
    SB();
    AC(E0, V0)                 // waits vmcnt(8)
    RD(2, E2)                  // ds for group 2 under remaining vm latency
    SB();
    LD(E2, V0)                 // refill freed V0 (8 outstanding + V1 pending)
    SB();
    AC(E1, V1)
    RD(3, E3)
    SB();
    LD(E3, V1)
    SB();
    AC(E2, V0)
    AC(E3, V1)

    // merge x0/x1 partials: partner lane is j ^ 4
#pragma unroll
    for (int k = 0; k < 8; ++k)
        acc[k] += __shfl_xor(acc[k], 4);

    f32x4 st;
    st.x = acc[side * 4 + 0];
    st.y = acc[side * 4 + 1];
    st.z = acc[side * 4 + 2];
    st.w = acc[side * 4 + 3];
    const size_t onqh = ((size_t)n * Lq + q) * NH + h;
    __builtin_nontemporal_store(st, (f32x4*)(out + onqh * DD + cg * 8 + side * 4));
}

// ---------------- fp32 fallback if ws too small ----------------
__global__ __launch_bounds__(256) void msda_fwd_f32(
    const float* __restrict__ value,
    const int*   __restrict__ spatial_shapes,
    const int*   __restrict__ level_start,
    const float* __restrict__ sloc,
    const float* __restrict__ aw,
    float*       __restrict__ out,
    int N, int Lq, int Lin, int total)
{
    int tid = blockIdx.x * blockDim.x + threadIdx.x;
    if (tid >= total) return;
    const int c  = tid & 7;
    const int h  = (tid >> 3) & 7;
    const int nq = tid >> 6;
    const int n  = nq / Lq;
    const bool is64 = (spatial_shapes[1] == 0);
    int Hs[LL], Ws[LL], Ss[LL];
#pragma unroll
    for (int l = 0; l < LL; ++l) {
        if (is64) { Hs[l] = spatial_shapes[4*l]; Ws[l] = spatial_shapes[4*l+2]; Ss[l] = level_start[2*l]; }
        else      { Hs[l] = spatial_shapes[2*l]; Ws[l] = spatial_shapes[2*l+1]; Ss[l] = level_start[l]; }
    }
    const size_t nqh = (size_t)nq * NH + h;
    const float* loc_p = sloc + nqh * (LL * PP * 2);
    const float* aw_p  = aw   + nqh * (LL * PP);
    float4 acc = make_float4(0.f, 0.f, 0.f, 0.f);
#pragma unroll
    for (int l = 0; l < LL; ++l) {
        const int H = Hs[l], W = Ws[l];
        const float* vb = value + (((size_t)n * Lin + Ss[l]) * NH + h) * DD + c * 4;
#pragma unroll
        for (int p = 0; p < PP; ++p) {
            const int jj = l * PP + p;
            const float x = loc_p[2*jj] * (float)W - 0.5f;
            const float y = loc_p[2*jj+1] * (float)H - 0.5f;
            const float w = aw_p[jj];
            const float x0f = floorf(x), y0f = floorf(y);
            const int x0 = (int)x0f, y0 = (int)y0f, x1 = x0+1, y1 = y0+1;
            const float dx = x - x0f, dy = y - y0f;
            const bool vx0 = x0>=0 && x0<W, vx1 = x1>=0 && x1<W;
            const bool vy0 = y0>=0 && y0<H, vy1 = y1>=0 && y1<H;
            const int cx0 = min(max(x0,0),W-1), cx1 = min(max(x1,0),W-1);
            const int cy0 = min(max(y0,0),H-1), cy1 = min(max(y1,0),H-1);
            const float w00 = (1.f-dx)*(1.f-dy)*w*((vx0&&vy0)?1.f:0.f);
            const float w01 = dx*(1.f-dy)*w*((vx1&&vy0)?1.f:0.f);
            const float w10 = (1.f-dx)*dy*w*((vx0&&vy1)?1.f:0.f);
            const float w11 = dx*dy*w*((vx1&&vy1)?1.f:0.f);
            const float4 v00 = *(const float4*)(vb + (size_t)(cy0*W+cx0)*(NH*DD));
            const float4 v01 = *(const float4*)(vb + (size_t)(cy0*W+cx1)*(NH*DD));
            const float4 v10 = *(const float4*)(vb + (size_t)(cy1*W+cx0)*(NH*DD));
            const float4 v11 = *(const float4*)(vb + (size_t)(cy1*W+cx1)*(NH*DD));
            acc.x += w00*v00.x + w01*v01.x + w10*v10.x + w11*v11.x;
            acc.y += w00*v00.y + w01*v01.y + w10*v10.y + w11*v11.y;
            acc.z += w00*v00.z + w01*v01.z + w10*v10.z + w11*v11.z;
            acc.w += w00*v00.w + w01*v01.w + w10*v10.w + w11*v11.w;
        }
    }
    *(float4*)(out + nqh * DD + c * 4) = acc;
}

extern "C" void kernel_launch(void* const* d_in, const int* in_sizes, int n_in,
                              void* d_out, int out_size, void* d_ws, size_t ws_size,
                              hipStream_t stream)
{
    const float* value = (const float*)d_in[0];
    const int*   ss    = (const int*)  d_in[1];
    const int*   lsi   = (const int*)  d_in[2];
    const float* sloc  = (const float*)d_in[3];
    const float* aw    = (const float*)d_in[4];
    float* out = (float*)d_out;

    const int N = 2;
    const int Lq  = in_sizes[4] / (N * NH * LL * PP);
    const int Lin = in_sizes[0] / (N * NH * DD);

    const size_t need = (size_t)N * NH * Lin * DD * sizeof(_Float16);
    if (ws_size >= need) {
        _Float16* vh = (_Float16*)d_ws;
        const int nSlabs = N * NH;              // 16
        const int spx    = (nSlabs + 7) / 8;    // slabs per XCD = 2
        const int segs   = (Lin * 8 + 255) / 256;
        conv_kernel<<<8 * spx * segs, 256, 0, stream>>>(value, vh, Lin, spx, nSlabs);

        const int chunks = (Lq + 31) / 32;
        const int grid   = 8 * spx * chunks;
        msda_fwd_h<<<grid, 256, 0, stream>>>(vh, ss, lsi, sloc, aw, out,
                                             N, Lq, Lin, spx, chunks, nSlabs);
    } else {
        const int total = N * Lq * NH * 8;
        msda_fwd_f32<<<(total + 255) / 256, 256, 0, stream>>>(value, ss, lsi, sloc, aw, out,
                                                              N, Lq, Lin, total);
    }
}